// Round 1
// baseline (1375.443 us; speedup 1.0000x reference)
//
#include <hip/hip_runtime.h>
#include <cmath>

// PoincareConcatLinear  (C=1 => RC=1)
// x[N,8,128] f32, weight_g[1024], weight_v[1024,1024], bias[1024] -> out[N,1024] f32
//
// Pipeline:
//   k_wprep : wn = colnormalize(weight_v); cc=cosh(2b), sb=sinh(2b), gg=2*wg
//   k_tprep : per-token logmap0(per stack) -> *beta_ratio -> expmap0 -> y, cx2
//   k_gemm  : h = epilogue( y @ wn )   (written to d_out)
//   k_proj  : out = h / (1 + sqrt(1 + sum h^2))   (in-place on d_out)

constexpr int SD   = 1024;   // S*D
constexpr int OUTD = 1024;   // OUT

// ---------------------------------------------------------------- weight prep
__global__ __launch_bounds__(256) void k_wprep(
    const float* __restrict__ wv, const float* __restrict__ wg,
    const float* __restrict__ bias,
    float* __restrict__ wn, float* __restrict__ cc,
    float* __restrict__ sb, float* __restrict__ gg)
{
    const int j = blockIdx.x;      // output column
    const int t = threadIdx.x;     // 256 threads
    float s = 0.f;
    for (int i = t; i < SD; i += 256) {
        float v = wv[(size_t)i * OUTD + j];
        s += v * v;
    }
    __shared__ float red[256];
    red[t] = s;
    __syncthreads();
    for (int off = 128; off > 0; off >>= 1) {
        if (t < off) red[t] += red[t + off];
        __syncthreads();
    }
    const float rn = 1.0f / fmaxf(sqrtf(red[0]), 1e-15f);
    for (int i = t; i < SD; i += 256)
        wn[(size_t)i * OUTD + j] = wv[(size_t)i * OUTD + j] * rn;
    if (t == 0) {
        float b2 = 2.0f * bias[j];
        cc[j] = coshf(b2);
        sb[j] = sinhf(b2);
        gg[j] = 2.0f * wg[j];
    }
}

// ---------------------------------------------------------------- token prep
// one wave (64 lanes) per token; lane holds 16 contiguous floats.
// stack s (128 elems) = lanes [8s, 8s+8)
__global__ __launch_bounds__(256) void k_tprep(
    const float* __restrict__ x, float* __restrict__ y,
    float* __restrict__ cx2, float beta_ratio, int ntok)
{
    const int wid  = threadIdx.x >> 6;
    const int lane = threadIdx.x & 63;
    const int tok  = blockIdx.x * 4 + wid;
    if (tok >= ntok) return;

    const float* xp = x + (size_t)tok * SD + lane * 16;
    float u[16];
    float4* uv = (float4*)u;
    uv[0] = *(const float4*)(xp + 0);
    uv[1] = *(const float4*)(xp + 4);
    uv[2] = *(const float4*)(xp + 8);
    uv[3] = *(const float4*)(xp + 12);

    // per-stack norm (8 lanes per stack)
    float ssq = 0.f;
#pragma unroll
    for (int k = 0; k < 16; ++k) ssq += u[k] * u[k];
    ssq += __shfl_xor(ssq, 1);
    ssq += __shfl_xor(ssq, 2);
    ssq += __shfl_xor(ssq, 4);
    const float xn = fmaxf(sqrtf(ssq), 1e-15f);
    const float ts = atanhf(fminf(xn, 1.0f - 1e-7f)) / xn * beta_ratio;
#pragma unroll
    for (int k = 0; k < 16; ++k) u[k] *= ts;

    // full-vector norm (all 64 lanes)
    float usq = 0.f;
#pragma unroll
    for (int k = 0; k < 16; ++k) usq += u[k] * u[k];
    usq += __shfl_xor(usq, 1);
    usq += __shfl_xor(usq, 2);
    usq += __shfl_xor(usq, 4);
    usq += __shfl_xor(usq, 8);
    usq += __shfl_xor(usq, 16);
    usq += __shfl_xor(usq, 32);
    const float un  = fmaxf(sqrtf(usq), 1e-15f);
    const float esc = tanhf(un) / un;
#pragma unroll
    for (int k = 0; k < 16; ++k) u[k] *= esc;

    float* yp = y + (size_t)tok * SD + lane * 16;
    ((float4*)yp)[0] = uv[0];
    ((float4*)yp)[1] = uv[1];
    ((float4*)yp)[2] = uv[2];
    ((float4*)yp)[3] = uv[3];
    if (lane == 0) cx2[tok] = esc * esc * usq;   // == sum(y^2)
}

// ---------------------------------------------------------------- GEMM + MLR
// 64x64 tile, BK=16, 256 threads, 4x4 micro-tile per thread. fp32 VALU.
__global__ __launch_bounds__(256) void k_gemm(
    const float* __restrict__ A,   // y  [ntok][1024]
    const float* __restrict__ B,   // wn [1024][1024]
    const float* __restrict__ cx2,
    const float* __restrict__ cc, const float* __restrict__ sb,
    const float* __restrict__ gg,
    float* __restrict__ H)         // d_out, holds h
{
    constexpr int BM = 64, BN = 64, BK = 16;
    __shared__ float As[BK][BM];   // stored K-major (transposed)
    __shared__ float Bs[BK][BN];

    const int bx = blockIdx.x & 15;        // 1024/64 = 16 col tiles
    const int by = blockIdx.x >> 4;
    const int t  = threadIdx.x;
    const int tx = t & 15;                 // 16 col-threads
    const int ty = t >> 4;                 // 16 row-threads
    const int row0 = by * BM, col0 = bx * BN;

    const int ar = t >> 2;                 // 0..63  tile row for A load
    const int ac = (t & 3) * 4;            // 0,4,8,12 k-offset (float4)
    const int br = t >> 4;                 // 0..15  k for B load
    const int bc = (t & 15) * 4;           // col offset (float4)

    float acc[4][4] = {};

    for (int k0 = 0; k0 < SD; k0 += BK) {
        float4 a = *(const float4*)(A + (size_t)(row0 + ar) * SD + k0 + ac);
        float4 b = *(const float4*)(B + (size_t)(k0 + br) * OUTD + col0 + bc);
        As[ac + 0][ar] = a.x;
        As[ac + 1][ar] = a.y;
        As[ac + 2][ar] = a.z;
        As[ac + 3][ar] = a.w;
        *(float4*)&Bs[br][bc] = b;
        __syncthreads();
#pragma unroll
        for (int kk = 0; kk < BK; ++kk) {
            float av[4], bv[4];
            *(float4*)av = *(const float4*)&As[kk][ty * 4];
            *(float4*)bv = *(const float4*)&Bs[kk][tx * 4];
#pragma unroll
            for (int i = 0; i < 4; ++i)
#pragma unroll
                for (int j = 0; j < 4; ++j)
                    acc[i][j] = fmaf(av[i], bv[j], acc[i][j]);
        }
        __syncthreads();
    }

    // fused MLR epilogue -> h
#pragma unroll
    for (int i = 0; i < 4; ++i) {
        const int r = row0 + ty * 4 + i;
        const float c2  = cx2[r];
        const float omc = fmaxf(1.0f - c2, 1e-15f);
        const float opc = 1.0f + c2;
        float4 o;
        float* op = &o.x;
#pragma unroll
        for (int j = 0; j < 4; ++j) {
            const int c = col0 + tx * 4 + j;
            float num = 2.0f * acc[i][j] * cc[c] - opc * sb[c];
            float h = gg[c] * asinhf(num / omc);
            if (!isfinite(h)) h = 0.0f;
            h = sinhf(fminf(fmaxf(h, -20.0f), 20.0f));
            if (!isfinite(h)) h = 0.0f;
            op[j] = h;
        }
        *(float4*)(H + (size_t)r * OUTD + col0 + tx * 4) = o;
    }
}

// ---------------------------------------------------------------- projection
// wave per row, in-place on d_out
__global__ __launch_bounds__(256) void k_proj(float* __restrict__ H, int ntok)
{
    const int wid  = threadIdx.x >> 6;
    const int lane = threadIdx.x & 63;
    const int tok  = blockIdx.x * 4 + wid;
    if (tok >= ntok) return;

    float* hp = H + (size_t)tok * OUTD + lane * 16;
    float h[16];
    float4* hv = (float4*)h;
    hv[0] = *(const float4*)(hp + 0);
    hv[1] = *(const float4*)(hp + 4);
    hv[2] = *(const float4*)(hp + 8);
    hv[3] = *(const float4*)(hp + 12);

    float s = 0.f;
#pragma unroll
    for (int k = 0; k < 16; ++k) s += h[k] * h[k];
    s += __shfl_xor(s, 1);
    s += __shfl_xor(s, 2);
    s += __shfl_xor(s, 4);
    s += __shfl_xor(s, 8);
    s += __shfl_xor(s, 16);
    s += __shfl_xor(s, 32);
    const float n2 = fminf(s, 1e15f);
    const float rs = 1.0f / (1.0f + sqrtf(1.0f + n2));
#pragma unroll
    for (int k = 0; k < 16; ++k) {
        float r = h[k] * rs;
        if (!isfinite(r)) r = 0.0f;
        h[k] = r;
    }
    ((float4*)hp)[0] = hv[0];
    ((float4*)hp)[1] = hv[1];
    ((float4*)hp)[2] = hv[2];
    ((float4*)hp)[3] = hv[3];
}

// ---------------------------------------------------------------- launch
extern "C" void kernel_launch(void* const* d_in, const int* in_sizes, int n_in,
                              void* d_out, int out_size, void* d_ws, size_t ws_size,
                              hipStream_t stream)
{
    const float* x    = (const float*)d_in[0];
    const float* wg   = (const float*)d_in[1];
    const float* wv   = (const float*)d_in[2];
    const float* bias = (const float*)d_in[3];
    float* out = (float*)d_out;

    const int ntok = in_sizes[0] / SD;   // 32768

    // workspace layout (floats):
    //   y   : ntok*1024
    //   wn  : 1024*1024
    //   cx2 : ntok
    //   cc/sb/gg : 1024 each
    float* y   = (float*)d_ws;
    float* wn  = y + (size_t)ntok * SD;
    float* cx2 = wn + (size_t)SD * OUTD;
    float* cc  = cx2 + ntok;
    float* sb  = cc + OUTD;
    float* gg  = sb + OUTD;

    // beta ratio = B(S*D/2, 1/2) / B(D/2, 1/2)  (lgamma(0.5) cancels)
    const double lg = (lgamma(512.0) - lgamma(512.5)) - (lgamma(64.0) - lgamma(64.5));
    const float beta_ratio = (float)exp(lg);

    k_wprep<<<OUTD, 256, 0, stream>>>(wv, wg, bias, wn, cc, sb, gg);
    k_tprep<<<(ntok + 3) / 4, 256, 0, stream>>>(x, y, cx2, beta_ratio, ntok);
    k_gemm<<<(ntok / 64) * (OUTD / 64), 256, 0, stream>>>(y, wn, cx2, cc, sb, gg, out);
    k_proj<<<(ntok + 3) / 4, 256, 0, stream>>>(out, ntok);
}

// Round 4
// 1151.128 us; speedup vs baseline: 1.1949x; 1.1949x over previous
//
#include <hip/hip_runtime.h>
#include <hip/hip_bf16.h>
#include <cmath>

// PoincareConcatLinear (C=1 => RC=1)
// x[N,8,128] f32, weight_g[1024], weight_v[1024,1024], bias[1024] -> out[N,1024] f32
//
//   k_wprep : wnT[j][i] = colnorm(weight_v)  (bf16, TRANSPOSED); cc/sb/gg params
//   k_tprep : logmap0 -> beta -> expmap0 -> y (bf16), cx2 (f32)
//   k_gemm  : h = MLR-epilogue( y @ wn )  via bf16 MFMA, 128x128 tile -> d_out
//   k_proj  : out = h / (1 + sqrt(1 + sum h^2))  in-place

constexpr int SD   = 1024;
constexpr int OUTD = 1024;

typedef __attribute__((ext_vector_type(4))) float f32x4;
typedef __attribute__((ext_vector_type(8))) short s16x8;

__device__ __forceinline__ void gload16(const void* g, void* l) {
    __builtin_amdgcn_global_load_lds(
        (const __attribute__((address_space(1))) unsigned int*)g,
        (__attribute__((address_space(3))) unsigned int*)l, 16, 0, 0);
}

// ---------------------------------------------------------------- weight prep
__global__ __launch_bounds__(256) void k_wprep(
    const float* __restrict__ wv, const float* __restrict__ wg,
    const float* __restrict__ bias,
    __hip_bfloat16* __restrict__ wnT, float* __restrict__ cc,
    float* __restrict__ sb, float* __restrict__ gg)
{
    const int j = blockIdx.x;      // output column
    const int t = threadIdx.x;
    float v[4];
    float s = 0.f;
#pragma unroll
    for (int i = 0; i < 4; ++i) {
        v[i] = wv[(size_t)(t + i * 256) * OUTD + j];
        s += v[i] * v[i];
    }
    __shared__ float red[256];
    red[t] = s;
    __syncthreads();
    for (int off = 128; off > 0; off >>= 1) {
        if (t < off) red[t] += red[t + off];
        __syncthreads();
    }
    const float rn = 1.0f / fmaxf(sqrtf(red[0]), 1e-15f);
#pragma unroll
    for (int i = 0; i < 4; ++i)
        wnT[(size_t)j * SD + t + i * 256] = __float2bfloat16(v[i] * rn);
    if (t == 0) {
        float b2 = 2.0f * bias[j];
        cc[j] = coshf(b2);
        sb[j] = sinhf(b2);
        gg[j] = 2.0f * wg[j];
    }
}

// ---------------------------------------------------------------- token prep
// one wave per token; lane holds 16 contiguous floats; stack = 8 lanes
__global__ __launch_bounds__(256) void k_tprep(
    const float* __restrict__ x, __hip_bfloat16* __restrict__ y,
    float* __restrict__ cx2, float beta_ratio, int ntok)
{
    const int wid  = threadIdx.x >> 6;
    const int lane = threadIdx.x & 63;
    const int tok  = blockIdx.x * 4 + wid;
    if (tok >= ntok) return;

    const float* xp = x + (size_t)tok * SD + lane * 16;
    float u[16];
    f32x4* uv = (f32x4*)u;
    uv[0] = *(const f32x4*)(xp + 0);
    uv[1] = *(const f32x4*)(xp + 4);
    uv[2] = *(const f32x4*)(xp + 8);
    uv[3] = *(const f32x4*)(xp + 12);

    float ssq = 0.f;
#pragma unroll
    for (int k = 0; k < 16; ++k) ssq += u[k] * u[k];
    ssq += __shfl_xor(ssq, 1);
    ssq += __shfl_xor(ssq, 2);
    ssq += __shfl_xor(ssq, 4);
    const float xn = fmaxf(sqrtf(ssq), 1e-15f);
    const float ts = atanhf(fminf(xn, 1.0f - 1e-7f)) / xn * beta_ratio;
#pragma unroll
    for (int k = 0; k < 16; ++k) u[k] *= ts;

    float usq = 0.f;
#pragma unroll
    for (int k = 0; k < 16; ++k) usq += u[k] * u[k];
    usq += __shfl_xor(usq, 1);
    usq += __shfl_xor(usq, 2);
    usq += __shfl_xor(usq, 4);
    usq += __shfl_xor(usq, 8);
    usq += __shfl_xor(usq, 16);
    usq += __shfl_xor(usq, 32);
    const float un  = fmaxf(sqrtf(usq), 1e-15f);
    const float esc = tanhf(un) / un;

    __hip_bfloat16 yb[16];
#pragma unroll
    for (int k = 0; k < 16; ++k) yb[k] = __float2bfloat16(u[k] * esc);

    __hip_bfloat16* yp = y + (size_t)tok * SD + lane * 16;
    ((s16x8*)yp)[0] = ((s16x8*)yb)[0];
    ((s16x8*)yp)[1] = ((s16x8*)yb)[1];
    if (lane == 0) cx2[tok] = esc * esc * usq;
}

// ---------------------------------------------------------------- GEMM + MLR
// 128x128 tile, BK=64, 256 thr = 4 waves (2x2), 4x4 x mfma_16x16x32_bf16/wave.
// LDS both tiles [row-or-col][K] with 16B-chunk XOR swizzle (chunk ^= row&7);
// global source pre-swizzled so global_load_lds stays linear (rule #21).
__global__ __launch_bounds__(256) void k_gemm(
    const __hip_bfloat16* __restrict__ A,   // y  [M][1024]
    const __hip_bfloat16* __restrict__ BT,  // wnT [1024][1024] = wn^T
    const float* __restrict__ cx2,
    const float* __restrict__ cc, const float* __restrict__ sb,
    const float* __restrict__ gg,
    float* __restrict__ H)
{
    constexpr int BK = 64;
    __shared__ __hip_bfloat16 As[128 * BK];
    __shared__ __hip_bfloat16 Bs[128 * BK];

    const int tid  = threadIdx.x;
    const int lane = tid & 63;
    const int wave = tid >> 6;
    const int wr = wave >> 1, wc = wave & 1;

    // bijective XCD swizzle: 2048 blocks, 8 XCDs, 256-block chunks.
    // consecutive logical ids share the A row-panel -> same XCD L2.
    const int nwg = gridDim.x;
    const int L   = (blockIdx.x & 7) * (nwg >> 3) + (blockIdx.x >> 3);
    const int bx  = L & 7;          // 8 col tiles
    const int by  = L >> 3;         // row tiles
    const size_t row0 = (size_t)by * 128;
    const int    col0 = bx * 128;

    f32x4 acc[4][4] = {};

    const char* Ab  = (const char*)A;
    const char* Bb  = (const char*)BT;
    char* AsB = (char*)As;
    char* BsB = (char*)Bs;

    for (int k0 = 0; k0 < SD; k0 += BK) {
#pragma unroll
        for (int i = 0; i < 4; ++i) {
            const int f  = i * 256 + tid;       // 16B-chunk index, 0..1023
            const int r  = f >> 3;              // tile row (A) / tile col (B)
            const int ch = (f & 7) ^ (r & 7);   // pre-swizzled global chunk
            gload16(Ab + ((row0 + r) * SD + k0) * 2 + ch * 16, AsB + f * 16);
            gload16(Bb + ((size_t)(col0 + r) * SD + k0) * 2 + ch * 16, BsB + f * 16);
        }
        __syncthreads();
#pragma unroll
        for (int ks = 0; ks < 2; ++ks) {
            s16x8 av[4], bv[4];
            const int g = ks * 4 + (lane >> 4);   // k-chunk 0..7
#pragma unroll
            for (int m = 0; m < 4; ++m) {
                const int rr = wr * 64 + m * 16 + (lane & 15);
                av[m] = *(const s16x8*)(AsB + rr * 128 + ((g ^ (rr & 7)) << 4));
                const int rc = wc * 64 + m * 16 + (lane & 15);
                bv[m] = *(const s16x8*)(BsB + rc * 128 + ((g ^ (rc & 7)) << 4));
            }
#pragma unroll
            for (int m = 0; m < 4; ++m)
#pragma unroll
                for (int n = 0; n < 4; ++n)
                    acc[m][n] = __builtin_amdgcn_mfma_f32_16x16x32_bf16(
                        av[m], bv[n], acc[m][n], 0, 0, 0);
        }
        __syncthreads();
    }

    // fused MLR epilogue.  C/D frag: col = lane&15, row = (lane>>4)*4 + reg
    float ccv[4], sbv[4], ggv[4];
    int   gcv[4];
#pragma unroll
    for (int n = 0; n < 4; ++n) {
        gcv[n] = col0 + wc * 64 + n * 16 + (lane & 15);
        ccv[n] = cc[gcv[n]];
        sbv[n] = sb[gcv[n]];
        ggv[n] = gg[gcv[n]];
    }
#pragma unroll
    for (int m = 0; m < 4; ++m) {
        const size_t gr0 = row0 + wr * 64 + m * 16 + (lane >> 4) * 4;
#pragma unroll
        for (int r = 0; r < 4; ++r) {
            const size_t gr  = gr0 + r;
            const float c2   = cx2[gr];
            const float omc  = fmaxf(1.0f - c2, 1e-15f);
            const float opc  = 1.0f + c2;
#pragma unroll
            for (int n = 0; n < 4; ++n) {
                float num = 2.0f * acc[m][n][r] * ccv[n] - opc * sbv[n];
                float h = ggv[n] * asinhf(num / omc);
                if (!isfinite(h)) h = 0.0f;
                h = sinhf(fminf(fmaxf(h, -20.0f), 20.0f));
                if (!isfinite(h)) h = 0.0f;
                H[gr * OUTD + gcv[n]] = h;
            }
        }
    }
}

// ---------------------------------------------------------------- projection
__global__ __launch_bounds__(256) void k_proj(float* __restrict__ H, int ntok)
{
    const int wid  = threadIdx.x >> 6;
    const int lane = threadIdx.x & 63;
    const int tok  = blockIdx.x * 4 + wid;
    if (tok >= ntok) return;

    float* hp = H + (size_t)tok * OUTD + lane * 16;
    float h[16];
    f32x4* hv = (f32x4*)h;
    hv[0] = *(const f32x4*)(hp + 0);
    hv[1] = *(const f32x4*)(hp + 4);
    hv[2] = *(const f32x4*)(hp + 8);
    hv[3] = *(const f32x4*)(hp + 12);

    float s = 0.f;
#pragma unroll
    for (int k = 0; k < 16; ++k) s += h[k] * h[k];
    s += __shfl_xor(s, 1);
    s += __shfl_xor(s, 2);
    s += __shfl_xor(s, 4);
    s += __shfl_xor(s, 8);
    s += __shfl_xor(s, 16);
    s += __shfl_xor(s, 32);
    const float n2 = fminf(s, 1e15f);
    const float rs = 1.0f / (1.0f + sqrtf(1.0f + n2));
#pragma unroll
    for (int k = 0; k < 16; ++k) {
        float r = h[k] * rs;
        if (!isfinite(r)) r = 0.0f;
        h[k] = r;
    }
    ((f32x4*)hp)[0] = hv[0];
    ((f32x4*)hp)[1] = hv[1];
    ((f32x4*)hp)[2] = hv[2];
    ((f32x4*)hp)[3] = hv[3];
}

// ---------------------------------------------------------------- launch
extern "C" void kernel_launch(void* const* d_in, const int* in_sizes, int n_in,
                              void* d_out, int out_size, void* d_ws, size_t ws_size,
                              hipStream_t stream)
{
    const float* x    = (const float*)d_in[0];
    const float* wg   = (const float*)d_in[1];
    const float* wv   = (const float*)d_in[2];
    const float* bias = (const float*)d_in[3];
    float* out = (float*)d_out;

    const int ntok = in_sizes[0] / SD;   // 32768

    // workspace layout:
    //   y   : ntok*1024  bf16
    //   wnT : 1024*1024  bf16
    //   cx2 : ntok f32 ; cc/sb/gg : 1024 f32 each
    __hip_bfloat16* y   = (__hip_bfloat16*)d_ws;
    __hip_bfloat16* wnT = y + (size_t)ntok * SD;
    float* cx2 = (float*)(wnT + (size_t)SD * OUTD);
    float* cc  = cx2 + ntok;
    float* sb  = cc + OUTD;
    float* gg  = sb + OUTD;

    const double lg = (lgamma(512.0) - lgamma(512.5)) - (lgamma(64.0) - lgamma(64.5));
    const float beta_ratio = (float)exp(lg);

    k_wprep<<<OUTD, 256, 0, stream>>>(wv, wg, bias, wnT, cc, sb, gg);
    k_tprep<<<(ntok + 3) / 4, 256, 0, stream>>>(x, y, cx2, beta_ratio, ntok);
    k_gemm<<<(ntok / 128) * (OUTD / 128), 256, 0, stream>>>(y, wnT, cx2, cc, sb, gg, out);
    k_proj<<<(ntok + 3) / 4, 256, 0, stream>>>(out, ntok);
}

// Round 10
// 550.302 us; speedup vs baseline: 2.4994x; 2.0918x over previous
//
#include <hip/hip_runtime.h>
#include <hip/hip_bf16.h>
#include <cmath>

// PoincareConcatLinear (C=1 => RC=1)
// x[N,8,128] f32, weight_g[1024], weight_v[1024,1024], bias[1024] -> out[N,1024] f32
//
//   k_wprep : wnT = colnorm(weight_v)^T (bf16); cc/sb/gg params
//   k_tprep : logmap0 -> beta -> expmap0 -> y (bf16), cx2 (f32)
//   k_gemm  : h = MLR-epilogue( y @ wn )  bf16 MFMA 128x128 tile -> d_out
//   k_proj  : out = h / (1 + sqrt(1 + sum h^2)) in-place
//
// R5 experiment: eliminate scratch spill in k_gemm (R4: WRITE_SIZE 2.42 GiB =
// 19x output => ext-vector arrays in local memory, rule #20). All MFMA-path
// state is now NAMED registers; vector subscripts are literal-only;
// __launch_bounds__(256,2) pins the 256-VGPR budget.

constexpr int SD   = 1024;
constexpr int OUTD = 1024;

typedef __attribute__((ext_vector_type(4))) float f32x4;
typedef __attribute__((ext_vector_type(8))) short s16x8;

__device__ __forceinline__ void gload16(const void* g, void* l) {
    __builtin_amdgcn_global_load_lds(
        (const __attribute__((address_space(1))) unsigned int*)g,
        (__attribute__((address_space(3))) unsigned int*)l, 16, 0, 0);
}

// ---------------------------------------------------------------- weight prep
__global__ __launch_bounds__(256) void k_wprep(
    const float* __restrict__ wv, const float* __restrict__ wg,
    const float* __restrict__ bias,
    __hip_bfloat16* __restrict__ wnT, float* __restrict__ cc,
    float* __restrict__ sb, float* __restrict__ gg)
{
    const int j = blockIdx.x;
    const int t = threadIdx.x;
    float v[4];
    float s = 0.f;
#pragma unroll
    for (int i = 0; i < 4; ++i) {
        v[i] = wv[(size_t)(t + i * 256) * OUTD + j];
        s += v[i] * v[i];
    }
    __shared__ float red[256];
    red[t] = s;
    __syncthreads();
    for (int off = 128; off > 0; off >>= 1) {
        if (t < off) red[t] += red[t + off];
        __syncthreads();
    }
    const float rn = 1.0f / fmaxf(sqrtf(red[0]), 1e-15f);
#pragma unroll
    for (int i = 0; i < 4; ++i)
        wnT[(size_t)j * SD + t + i * 256] = __float2bfloat16(v[i] * rn);
    if (t == 0) {
        float b2 = 2.0f * bias[j];
        cc[j] = coshf(b2);
        sb[j] = sinhf(b2);
        gg[j] = 2.0f * wg[j];
    }
}

// ---------------------------------------------------------------- token prep
__global__ __launch_bounds__(256) void k_tprep(
    const float* __restrict__ x, __hip_bfloat16* __restrict__ y,
    float* __restrict__ cx2, float beta_ratio, int ntok)
{
    const int wid  = threadIdx.x >> 6;
    const int lane = threadIdx.x & 63;
    const int tok  = blockIdx.x * 4 + wid;
    if (tok >= ntok) return;

    const float* xp = x + (size_t)tok * SD + lane * 16;
    float u[16];
    f32x4* uv = (f32x4*)u;
    uv[0] = *(const f32x4*)(xp + 0);
    uv[1] = *(const f32x4*)(xp + 4);
    uv[2] = *(const f32x4*)(xp + 8);
    uv[3] = *(const f32x4*)(xp + 12);

    float ssq = 0.f;
#pragma unroll
    for (int k = 0; k < 16; ++k) ssq += u[k] * u[k];
    ssq += __shfl_xor(ssq, 1);
    ssq += __shfl_xor(ssq, 2);
    ssq += __shfl_xor(ssq, 4);
    const float xn = fmaxf(sqrtf(ssq), 1e-15f);
    const float ts = atanhf(fminf(xn, 1.0f - 1e-7f)) / xn * beta_ratio;
#pragma unroll
    for (int k = 0; k < 16; ++k) u[k] *= ts;

    float usq = 0.f;
#pragma unroll
    for (int k = 0; k < 16; ++k) usq += u[k] * u[k];
    usq += __shfl_xor(usq, 1);
    usq += __shfl_xor(usq, 2);
    usq += __shfl_xor(usq, 4);
    usq += __shfl_xor(usq, 8);
    usq += __shfl_xor(usq, 16);
    usq += __shfl_xor(usq, 32);
    const float un  = fmaxf(sqrtf(usq), 1e-15f);
    const float esc = tanhf(un) / un;

    __hip_bfloat16 yb[16];
#pragma unroll
    for (int k = 0; k < 16; ++k) yb[k] = __float2bfloat16(u[k] * esc);

    __hip_bfloat16* yp = y + (size_t)tok * SD + lane * 16;
    ((s16x8*)yp)[0] = ((s16x8*)yb)[0];
    ((s16x8*)yp)[1] = ((s16x8*)yb)[1];
    if (lane == 0) cx2[tok] = esc * esc * usq;
}

// ---------------------------------------------------------------- GEMM + MLR
// 128x128 tile, BK=64, 4 waves (2x2), per wave 4x4 mfma_16x16x32_bf16.
// LDS 16B-chunk XOR swizzle, both-sides (pre-swizzled global src, rule #21).
// ALL per-thread MFMA state in named registers (R4 spill post-mortem).

#define FRAG(S, r, sl) (*(const s16x8*)&S[(r) * 64 + ((sl) << 3)])
#define MFMA(d, a, b) d = __builtin_amdgcn_mfma_f32_16x16x32_bf16(a, b, d, 0, 0, 0)

// one accumulator element -> h, stored
#define EPI_ONE(Hrow, AV, R, NC) do {                                   \
    float num_ = 2.0f * (AV)[R] * cb##NC - opc_ * sbb##NC;              \
    float h_ = gb##NC * asinhf(num_ / omc_);                            \
    if (!isfinite(h_)) h_ = 0.0f;                                       \
    h_ = sinhf(fminf(fmaxf(h_, -20.0f), 20.0f));                        \
    if (!isfinite(h_)) h_ = 0.0f;                                       \
    (Hrow)[gc##NC] = h_;                                                \
} while (0)

#define EPI_ROW(A0, A1, A2, A3, R) do {                                 \
    const size_t gr_ = grA_ + (R);                                      \
    const float c2_  = cx2[gr_];                                        \
    const float omc_ = fmaxf(1.0f - c2_, 1e-15f);                       \
    const float opc_ = 1.0f + c2_;                                      \
    float* Hrow_ = H + gr_ * OUTD;                                      \
    EPI_ONE(Hrow_, A0, R, 0); EPI_ONE(Hrow_, A1, R, 1);                 \
    EPI_ONE(Hrow_, A2, R, 2); EPI_ONE(Hrow_, A3, R, 3);                 \
} while (0)

#define EPI_M(A0, A1, A2, A3, M) do {                                   \
    const size_t grA_ = row0 + wr * 64 + (M) * 16 + (lane >> 4) * 4;    \
    EPI_ROW(A0, A1, A2, A3, 0); EPI_ROW(A0, A1, A2, A3, 1);             \
    EPI_ROW(A0, A1, A2, A3, 2); EPI_ROW(A0, A1, A2, A3, 3);             \
} while (0)

__global__ __launch_bounds__(256, 2) void k_gemm(
    const __hip_bfloat16* __restrict__ A,   // y  [M][1024]
    const __hip_bfloat16* __restrict__ BT,  // wnT [1024][1024]
    const float* __restrict__ cx2,
    const float* __restrict__ cc, const float* __restrict__ sb,
    const float* __restrict__ gg,
    float* __restrict__ H)
{
    constexpr int BK = 64;
    __shared__ __hip_bfloat16 As[128 * BK];
    __shared__ __hip_bfloat16 Bs[128 * BK];

    const int tid  = threadIdx.x;
    const int lane = tid & 63;
    const int wave = tid >> 6;
    const int wr = wave >> 1, wc = wave & 1;

    // bijective XCD swizzle (2048 blocks % 8 == 0): 256-block chunks per XCD
    const int nwg = gridDim.x;
    const int L   = (blockIdx.x & 7) * (nwg >> 3) + (blockIdx.x >> 3);
    const int bx  = L & 7;
    const int by  = L >> 3;
    const size_t row0 = (size_t)by * 128;
    const int    col0 = bx * 128;

    f32x4 c00{}, c01{}, c02{}, c03{};
    f32x4 c10{}, c11{}, c12{}, c13{};
    f32x4 c20{}, c21{}, c22{}, c23{};
    f32x4 c30{}, c31{}, c32{}, c33{};

    const char* Ab = (const char*)A;
    const char* Bb = (const char*)BT;

    // fragment row bases (same for every k-step)
    const int ra = wr * 64 + (lane & 15);
    const int rb = wc * 64 + (lane & 15);
    const int lxor = lane & 7;             // (row&7) == lane&7 for all frags

    for (int k0 = 0; k0 < SD; k0 += BK) {
#pragma unroll
        for (int i = 0; i < 4; ++i) {
            const int f  = i * 256 + tid;       // 16B chunk 0..1023
            const int r  = f >> 3;              // tile row
            const int ch = (f & 7) ^ (r & 7);   // pre-swizzled global chunk
            gload16(Ab + ((row0 + r) * SD + k0) * 2 + ch * 16, (char*)As + f * 16);
            gload16(Bb + ((size_t)(col0 + r) * SD + k0) * 2 + ch * 16, (char*)Bs + f * 16);
        }
        __syncthreads();
#pragma unroll
        for (int ks = 0; ks < 2; ++ks) {
            const int sl = (ks * 4 + (lane >> 4)) ^ lxor;   // swizzled k-slot
            const s16x8 a0 = FRAG(As, ra,      sl);
            const s16x8 a1 = FRAG(As, ra + 16, sl);
            const s16x8 a2 = FRAG(As, ra + 32, sl);
            const s16x8 a3 = FRAG(As, ra + 48, sl);
            const s16x8 b0 = FRAG(Bs, rb,      sl);
            const s16x8 b1 = FRAG(Bs, rb + 16, sl);
            const s16x8 b2 = FRAG(Bs, rb + 32, sl);
            const s16x8 b3 = FRAG(Bs, rb + 48, sl);
            MFMA(c00, a0, b0); MFMA(c01, a0, b1); MFMA(c02, a0, b2); MFMA(c03, a0, b3);
            MFMA(c10, a1, b0); MFMA(c11, a1, b1); MFMA(c12, a1, b2); MFMA(c13, a1, b3);
            MFMA(c20, a2, b0); MFMA(c21, a2, b1); MFMA(c22, a2, b2); MFMA(c23, a2, b3);
            MFMA(c30, a3, b0); MFMA(c31, a3, b1); MFMA(c32, a3, b2); MFMA(c33, a3, b3);
        }
        __syncthreads();
    }

    // fused MLR epilogue. C/D frag: col = lane&15, row = (lane>>4)*4 + reg
    const int gc0 = col0 + wc * 64 +  0 + (lane & 15);
    const int gc1 = gc0 + 16;
    const int gc2 = gc0 + 32;
    const int gc3 = gc0 + 48;
    const float cb0 = cc[gc0], cb1 = cc[gc1], cb2 = cc[gc2], cb3 = cc[gc3];
    const float sbb0 = sb[gc0], sbb1 = sb[gc1], sbb2 = sb[gc2], sbb3 = sb[gc3];
    const float gb0 = gg[gc0], gb1 = gg[gc1], gb2 = gg[gc2], gb3 = gg[gc3];

    EPI_M(c00, c01, c02, c03, 0);
    EPI_M(c10, c11, c12, c13, 1);
    EPI_M(c20, c21, c22, c23, 2);
    EPI_M(c30, c31, c32, c33, 3);
}

// ---------------------------------------------------------------- projection
__global__ __launch_bounds__(256) void k_proj(float* __restrict__ H, int ntok)
{
    const int wid  = threadIdx.x >> 6;
    const int lane = threadIdx.x & 63;
    const int tok  = blockIdx.x * 4 + wid;
    if (tok >= ntok) return;

    float* hp = H + (size_t)tok * OUTD + lane * 16;
    float h[16];
    f32x4* hv = (f32x4*)h;
    hv[0] = *(const f32x4*)(hp + 0);
    hv[1] = *(const f32x4*)(hp + 4);
    hv[2] = *(const f32x4*)(hp + 8);
    hv[3] = *(const f32x4*)(hp + 12);

    float s = 0.f;
#pragma unroll
    for (int k = 0; k < 16; ++k) s += h[k] * h[k];
    s += __shfl_xor(s, 1);
    s += __shfl_xor(s, 2);
    s += __shfl_xor(s, 4);
    s += __shfl_xor(s, 8);
    s += __shfl_xor(s, 16);
    s += __shfl_xor(s, 32);
    const float n2 = fminf(s, 1e15f);
    const float rs = 1.0f / (1.0f + sqrtf(1.0f + n2));
#pragma unroll
    for (int k = 0; k < 16; ++k) {
        float r = h[k] * rs;
        if (!isfinite(r)) r = 0.0f;
        h[k] = r;
    }
    ((f32x4*)hp)[0] = hv[0];
    ((f32x4*)hp)[1] = hv[1];
    ((f32x4*)hp)[2] = hv[2];
    ((f32x4*)hp)[3] = hv[3];
}

// ---------------------------------------------------------------- launch
extern "C" void kernel_launch(void* const* d_in, const int* in_sizes, int n_in,
                              void* d_out, int out_size, void* d_ws, size_t ws_size,
                              hipStream_t stream)
{
    const float* x    = (const float*)d_in[0];
    const float* wg   = (const float*)d_in[1];
    const float* wv   = (const float*)d_in[2];
    const float* bias = (const float*)d_in[3];
    float* out = (float*)d_out;

    const int ntok = in_sizes[0] / SD;   // 32768

    __hip_bfloat16* y   = (__hip_bfloat16*)d_ws;
    __hip_bfloat16* wnT = y + (size_t)ntok * SD;
    float* cx2 = (float*)(wnT + (size_t)SD * OUTD);
    float* cc  = cx2 + ntok;
    float* sb  = cc + OUTD;
    float* gg  = sb + OUTD;

    const double lg = (lgamma(512.0) - lgamma(512.5)) - (lgamma(64.0) - lgamma(64.5));
    const float beta_ratio = (float)exp(lg);

    k_wprep<<<OUTD, 256, 0, stream>>>(wv, wg, bias, wnT, cc, sb, gg);
    k_tprep<<<(ntok + 3) / 4, 256, 0, stream>>>(x, y, cx2, beta_ratio, ntok);
    k_gemm<<<(ntok / 128) * (OUTD / 128), 256, 0, stream>>>(y, wnT, cx2, cc, sb, gg, out);
    k_proj<<<(ntok + 3) / 4, 256, 0, stream>>>(out, ntok);
}

// Round 11
// 398.831 us; speedup vs baseline: 3.4487x; 1.3798x over previous
//
#include <hip/hip_runtime.h>
#include <hip/hip_bf16.h>
#include <cmath>

// PoincareConcatLinear (C=1 => RC=1)
// x[N,8,128] f32, weight_g[1024], weight_v[1024,1024], bias[1024] -> out[N,1024] f32
//
// R10 results: de-spill confirmed (WRITE 2.42GiB->128MiB, k_gemm 912->318us).
// New profile: VALUBusy 90.6%, MfmaUtil 9.5% -> precise-math epilogue is the
// bottleneck.
// R11 experiment: (1) fast transcendental epilogue (__logf/__expf/v_rcp,
// per-row reciprocal); (2) LDS double-buffer so global_load_lds latency hides
// under MFMA (barrier moved after compute).

constexpr int SD   = 1024;
constexpr int OUTD = 1024;

typedef __attribute__((ext_vector_type(4))) float f32x4;
typedef __attribute__((ext_vector_type(8))) short s16x8;

__device__ __forceinline__ void gload16(const void* g, void* l) {
    __builtin_amdgcn_global_load_lds(
        (const __attribute__((address_space(1))) unsigned int*)g,
        (__attribute__((address_space(3))) unsigned int*)l, 16, 0, 0);
}

__device__ __forceinline__ float fast_asinh(float z) {
    const float az = fabsf(z);
    const float r  = __logf(az + __builtin_amdgcn_sqrtf(fmaf(az, az, 1.0f)));
    return z < 0.0f ? -r : r;
}

// ---------------------------------------------------------------- weight prep
__global__ __launch_bounds__(256) void k_wprep(
    const float* __restrict__ wv, const float* __restrict__ wg,
    const float* __restrict__ bias,
    __hip_bfloat16* __restrict__ wnT, float* __restrict__ cc,
    float* __restrict__ sb, float* __restrict__ gg)
{
    const int j = blockIdx.x;
    const int t = threadIdx.x;
    float v[4];
    float s = 0.f;
#pragma unroll
    for (int i = 0; i < 4; ++i) {
        v[i] = wv[(size_t)(t + i * 256) * OUTD + j];
        s += v[i] * v[i];
    }
    __shared__ float red[256];
    red[t] = s;
    __syncthreads();
    for (int off = 128; off > 0; off >>= 1) {
        if (t < off) red[t] += red[t + off];
        __syncthreads();
    }
    const float rn = 1.0f / fmaxf(sqrtf(red[0]), 1e-15f);
#pragma unroll
    for (int i = 0; i < 4; ++i)
        wnT[(size_t)j * SD + t + i * 256] = __float2bfloat16(v[i] * rn);
    if (t == 0) {
        float b2 = 2.0f * bias[j];
        cc[j] = coshf(b2);
        sb[j] = sinhf(b2);
        gg[j] = 2.0f * wg[j];
    }
}

// ---------------------------------------------------------------- token prep
__global__ __launch_bounds__(256) void k_tprep(
    const float* __restrict__ x, __hip_bfloat16* __restrict__ y,
    float* __restrict__ cx2, float beta_ratio, int ntok)
{
    const int wid  = threadIdx.x >> 6;
    const int lane = threadIdx.x & 63;
    const int tok  = blockIdx.x * 4 + wid;
    if (tok >= ntok) return;

    const float* xp = x + (size_t)tok * SD + lane * 16;
    float u[16];
    f32x4* uv = (f32x4*)u;
    uv[0] = *(const f32x4*)(xp + 0);
    uv[1] = *(const f32x4*)(xp + 4);
    uv[2] = *(const f32x4*)(xp + 8);
    uv[3] = *(const f32x4*)(xp + 12);

    float ssq = 0.f;
#pragma unroll
    for (int k = 0; k < 16; ++k) ssq += u[k] * u[k];
    ssq += __shfl_xor(ssq, 1);
    ssq += __shfl_xor(ssq, 2);
    ssq += __shfl_xor(ssq, 4);
    const float xn = fmaxf(sqrtf(ssq), 1e-15f);
    const float ts = atanhf(fminf(xn, 1.0f - 1e-7f)) / xn * beta_ratio;
#pragma unroll
    for (int k = 0; k < 16; ++k) u[k] *= ts;

    float usq = 0.f;
#pragma unroll
    for (int k = 0; k < 16; ++k) usq += u[k] * u[k];
    usq += __shfl_xor(usq, 1);
    usq += __shfl_xor(usq, 2);
    usq += __shfl_xor(usq, 4);
    usq += __shfl_xor(usq, 8);
    usq += __shfl_xor(usq, 16);
    usq += __shfl_xor(usq, 32);
    const float un  = fmaxf(sqrtf(usq), 1e-15f);
    const float esc = tanhf(un) / un;

    __hip_bfloat16 yb[16];
#pragma unroll
    for (int k = 0; k < 16; ++k) yb[k] = __float2bfloat16(u[k] * esc);

    __hip_bfloat16* yp = y + (size_t)tok * SD + lane * 16;
    ((s16x8*)yp)[0] = ((s16x8*)yb)[0];
    ((s16x8*)yp)[1] = ((s16x8*)yb)[1];
    if (lane == 0) cx2[tok] = esc * esc * usq;
}

// ---------------------------------------------------------------- GEMM + MLR
// 128x128 tile, BK=64, 4 waves (2x2), per wave 4x4 mfma_16x16x32_bf16.
// LDS DOUBLE-BUFFERED (16KB x2 per operand): stage t+1 before computing t,
// single barrier per iter drains vmcnt after compute -> latency hidden.
// 16B-chunk XOR swizzle both-sides (pre-swizzled global src, rule #21).
// All MFMA state in named registers (R4 spill lesson).

#define FRAG(P, r, sl) (*(const s16x8*)((P) + (r) * 128 + ((sl) << 4)))
#define MFMA(d, a, b) d = __builtin_amdgcn_mfma_f32_16x16x32_bf16(a, b, d, 0, 0, 0)

#define STAGE(base, k0) do {                                            \
    _Pragma("unroll")                                                   \
    for (int i_ = 0; i_ < 4; ++i_) {                                    \
        const int f_  = i_ * 256 + tid;                                 \
        const int r_  = f_ >> 3;                                        \
        const int ch_ = (f_ & 7) ^ (r_ & 7);                            \
        gload16(Ab + ((row0 + r_) * SD + (k0)) * 2 + ch_ * 16,          \
                AsB + (base) + f_ * 16);                                \
        gload16(Bb + ((size_t)(col0 + r_) * SD + (k0)) * 2 + ch_ * 16,  \
                BsB + (base) + f_ * 16);                                \
    }                                                                   \
} while (0)

// fast-math MLR epilogue: one output element
#define EPI_ONE(Hrow, AV, R, NC) do {                                   \
    float num_ = fmaf(2.0f * (AV)[R], cb##NC, -opc_ * sbb##NC);         \
    float h_ = gb##NC * fast_asinh(num_ * rinv_);                       \
    if (!isfinite(h_)) h_ = 0.0f;                                       \
    h_ = fminf(fmaxf(h_, -20.0f), 20.0f);                               \
    const float e_ = __expf(h_);                                        \
    float s_ = 0.5f * (e_ - __builtin_amdgcn_rcpf(e_));                 \
    if (!isfinite(s_)) s_ = 0.0f;                                       \
    (Hrow)[gc##NC] = s_;                                                \
} while (0)

#define EPI_ROW(A0, A1, A2, A3, R) do {                                 \
    const size_t gr_ = grA_ + (R);                                      \
    const float c2_  = cx2[gr_];                                        \
    const float omc_ = fmaxf(1.0f - c2_, 1e-15f);                       \
    const float opc_ = 1.0f + c2_;                                      \
    const float rinv_ = 1.0f / omc_;                                    \
    float* Hrow_ = H + gr_ * OUTD;                                      \
    EPI_ONE(Hrow_, A0, R, 0); EPI_ONE(Hrow_, A1, R, 1);                 \
    EPI_ONE(Hrow_, A2, R, 2); EPI_ONE(Hrow_, A3, R, 3);                 \
} while (0)

#define EPI_M(A0, A1, A2, A3, M) do {                                   \
    const size_t grA_ = row0 + wr * 64 + (M) * 16 + (lane >> 4) * 4;    \
    EPI_ROW(A0, A1, A2, A3, 0); EPI_ROW(A0, A1, A2, A3, 1);             \
    EPI_ROW(A0, A1, A2, A3, 2); EPI_ROW(A0, A1, A2, A3, 3);             \
} while (0)

__global__ __launch_bounds__(256, 2) void k_gemm(
    const __hip_bfloat16* __restrict__ A,   // y  [M][1024]
    const __hip_bfloat16* __restrict__ BT,  // wnT [1024][1024]
    const float* __restrict__ cx2,
    const float* __restrict__ cc, const float* __restrict__ sb,
    const float* __restrict__ gg,
    float* __restrict__ H)
{
    constexpr int BK = 64;
    constexpr int BUFB = 128 * BK * 2;      // bytes per buffer (16 KB)
    __shared__ __hip_bfloat16 As[2 * 128 * BK];
    __shared__ __hip_bfloat16 Bs[2 * 128 * BK];

    const int tid  = threadIdx.x;
    const int lane = tid & 63;
    const int wave = tid >> 6;
    const int wr = wave >> 1, wc = wave & 1;

    // bijective XCD swizzle (2048 blocks % 8 == 0): 256-block chunks per XCD
    const int nwg = gridDim.x;
    const int L   = (blockIdx.x & 7) * (nwg >> 3) + (blockIdx.x >> 3);
    const int bx  = L & 7;
    const int by  = L >> 3;
    const size_t row0 = (size_t)by * 128;
    const int    col0 = bx * 128;

    f32x4 c00{}, c01{}, c02{}, c03{};
    f32x4 c10{}, c11{}, c12{}, c13{};
    f32x4 c20{}, c21{}, c22{}, c23{};
    f32x4 c30{}, c31{}, c32{}, c33{};

    const char* Ab = (const char*)A;
    const char* Bb = (const char*)BT;
    char* AsB = (char*)As;
    char* BsB = (char*)Bs;

    const int ra = wr * 64 + (lane & 15);   // fragment row bases
    const int rb = wc * 64 + (lane & 15);
    const int lxor = lane & 7;

    STAGE(0, 0);
    __syncthreads();

    int cur = 0;
#pragma unroll 1
    for (int t = 0; t < SD / BK; ++t) {
        const int nxt = cur ^ 1;
        if (t < SD / BK - 1) STAGE(nxt * BUFB, (t + 1) * BK);

        const char* Ap = AsB + cur * BUFB;
        const char* Bp = BsB + cur * BUFB;
#pragma unroll
        for (int ks = 0; ks < 2; ++ks) {
            const int sl = (ks * 4 + (lane >> 4)) ^ lxor;   // swizzled k-slot
            const s16x8 a0 = FRAG(Ap, ra,      sl);
            const s16x8 a1 = FRAG(Ap, ra + 16, sl);
            const s16x8 a2 = FRAG(Ap, ra + 32, sl);
            const s16x8 a3 = FRAG(Ap, ra + 48, sl);
            const s16x8 b0 = FRAG(Bp, rb,      sl);
            const s16x8 b1 = FRAG(Bp, rb + 16, sl);
            const s16x8 b2 = FRAG(Bp, rb + 32, sl);
            const s16x8 b3 = FRAG(Bp, rb + 48, sl);
            MFMA(c00, a0, b0); MFMA(c01, a0, b1); MFMA(c02, a0, b2); MFMA(c03, a0, b3);
            MFMA(c10, a1, b0); MFMA(c11, a1, b1); MFMA(c12, a1, b2); MFMA(c13, a1, b3);
            MFMA(c20, a2, b0); MFMA(c21, a2, b1); MFMA(c22, a2, b2); MFMA(c23, a2, b3);
            MFMA(c30, a3, b0); MFMA(c31, a3, b1); MFMA(c32, a3, b2); MFMA(c33, a3, b3);
        }
        __syncthreads();   // drains vmcnt: t+1 loads landed; all reads of cur done
        cur = nxt;
    }

    // fused MLR epilogue. C/D frag: col = lane&15, row = (lane>>4)*4 + reg
    const int gc0 = col0 + wc * 64 +  0 + (lane & 15);
    const int gc1 = gc0 + 16;
    const int gc2 = gc0 + 32;
    const int gc3 = gc0 + 48;
    const float cb0 = cc[gc0], cb1 = cc[gc1], cb2 = cc[gc2], cb3 = cc[gc3];
    const float sbb0 = sb[gc0], sbb1 = sb[gc1], sbb2 = sb[gc2], sbb3 = sb[gc3];
    const float gb0 = gg[gc0], gb1 = gg[gc1], gb2 = gg[gc2], gb3 = gg[gc3];

    EPI_M(c00, c01, c02, c03, 0);
    EPI_M(c10, c11, c12, c13, 1);
    EPI_M(c20, c21, c22, c23, 2);
    EPI_M(c30, c31, c32, c33, 3);
}

// ---------------------------------------------------------------- projection
__global__ __launch_bounds__(256) void k_proj(float* __restrict__ H, int ntok)
{
    const int wid  = threadIdx.x >> 6;
    const int lane = threadIdx.x & 63;
    const int tok  = blockIdx.x * 4 + wid;
    if (tok >= ntok) return;

    float* hp = H + (size_t)tok * OUTD + lane * 16;
    float h[16];
    f32x4* hv = (f32x4*)h;
    hv[0] = *(const f32x4*)(hp + 0);
    hv[1] = *(const f32x4*)(hp + 4);
    hv[2] = *(const f32x4*)(hp + 8);
    hv[3] = *(const f32x4*)(hp + 12);

    float s = 0.f;
#pragma unroll
    for (int k = 0; k < 16; ++k) s += h[k] * h[k];
    s += __shfl_xor(s, 1);
    s += __shfl_xor(s, 2);
    s += __shfl_xor(s, 4);
    s += __shfl_xor(s, 8);
    s += __shfl_xor(s, 16);
    s += __shfl_xor(s, 32);
    const float n2 = fminf(s, 1e15f);
    const float rs = 1.0f / (1.0f + sqrtf(1.0f + n2));
#pragma unroll
    for (int k = 0; k < 16; ++k) {
        float r = h[k] * rs;
        if (!isfinite(r)) r = 0.0f;
        h[k] = r;
    }
    ((f32x4*)hp)[0] = hv[0];
    ((f32x4*)hp)[1] = hv[1];
    ((f32x4*)hp)[2] = hv[2];
    ((f32x4*)hp)[3] = hv[3];
}

// ---------------------------------------------------------------- launch
extern "C" void kernel_launch(void* const* d_in, const int* in_sizes, int n_in,
                              void* d_out, int out_size, void* d_ws, size_t ws_size,
                              hipStream_t stream)
{
    const float* x    = (const float*)d_in[0];
    const float* wg   = (const float*)d_in[1];
    const float* wv   = (const float*)d_in[2];
    const float* bias = (const float*)d_in[3];
    float* out = (float*)d_out;

    const int ntok = in_sizes[0] / SD;   // 32768

    __hip_bfloat16* y   = (__hip_bfloat16*)d_ws;
    __hip_bfloat16* wnT = y + (size_t)ntok * SD;
    float* cx2 = (float*)(wnT + (size_t)SD * OUTD);
    float* cc  = cx2 + ntok;
    float* sb  = cc + OUTD;
    float* gg  = sb + OUTD;

    const double lg = (lgamma(512.0) - lgamma(512.5)) - (lgamma(64.0) - lgamma(64.5));
    const float beta_ratio = (float)exp(lg);

    k_wprep<<<OUTD, 256, 0, stream>>>(wv, wg, bias, wnT, cc, sb, gg);
    k_tprep<<<(ntok + 3) / 4, 256, 0, stream>>>(x, y, cx2, beta_ratio, ntok);
    k_gemm<<<(ntok / 128) * (OUTD / 128), 256, 0, stream>>>(y, wnT, cx2, cc, sb, gg, out);
    k_proj<<<(ntok + 3) / 4, 256, 0, stream>>>(out, ntok);
}

// Round 12
// 382.555 us; speedup vs baseline: 3.5954x; 1.0425x over previous
//
#include <hip/hip_runtime.h>
#include <hip/hip_bf16.h>
#include <cmath>

// PoincareConcatLinear (C=1 => RC=1)
// x[N,8,128] f32, weight_g[1024], weight_v[1024,1024], bias[1024] -> out[N,1024] f32
//
// R11 results: fast-epilogue+dbuf confirmed (k_gemm 318->128us, VALU 90->40%).
// Non-gemm portion now dominates: ~271us vs ~95us memory floor.
// R12 experiment: (1) k_tprep/k_proj interleaved-contiguous layout (lane-stride
// 16B instead of 64B -> full coalescing); fast atanh/tanh identities.
// (2) k_gemm: remove provably-dead isfinite guards in epilogue.

constexpr int SD   = 1024;
constexpr int OUTD = 1024;

typedef __attribute__((ext_vector_type(4))) float f32x4;
typedef __attribute__((ext_vector_type(8))) short s16x8;
typedef __attribute__((ext_vector_type(4))) short s16x4;

__device__ __forceinline__ void gload16(const void* g, void* l) {
    __builtin_amdgcn_global_load_lds(
        (const __attribute__((address_space(1))) unsigned int*)g,
        (__attribute__((address_space(3))) unsigned int*)l, 16, 0, 0);
}

__device__ __forceinline__ float fast_asinh(float z) {
    const float az = fabsf(z);
    const float r  = __logf(az + __builtin_amdgcn_sqrtf(fmaf(az, az, 1.0f)));
    return z < 0.0f ? -r : r;
}

// exact identity atanh(z) = 0.5*ln((1+z)/(1-z)); rcp+logf fast paths
__device__ __forceinline__ float fast_atanh(float z) {
    return 0.5f * __logf((1.0f + z) * __builtin_amdgcn_rcpf(1.0f - z));
}

__device__ __forceinline__ s16x4 to_bf16x4(f32x4 v, float sc) {
    s16x4 r;
    __hip_bfloat16 b;
    b = __float2bfloat16(v[0] * sc); r[0] = *(const short*)&b;
    b = __float2bfloat16(v[1] * sc); r[1] = *(const short*)&b;
    b = __float2bfloat16(v[2] * sc); r[2] = *(const short*)&b;
    b = __float2bfloat16(v[3] * sc); r[3] = *(const short*)&b;
    return r;
}

#define RED32(v) do { v += __shfl_xor(v, 1); v += __shfl_xor(v, 2);     \
                      v += __shfl_xor(v, 4); v += __shfl_xor(v, 8);     \
                      v += __shfl_xor(v, 16); } while (0)
#define RED64(v) do { RED32(v); v += __shfl_xor(v, 32); } while (0)

// ---------------------------------------------------------------- weight prep
__global__ __launch_bounds__(256) void k_wprep(
    const float* __restrict__ wv, const float* __restrict__ wg,
    const float* __restrict__ bias,
    __hip_bfloat16* __restrict__ wnT, float* __restrict__ cc,
    float* __restrict__ sb, float* __restrict__ gg)
{
    const int j = blockIdx.x;
    const int t = threadIdx.x;
    float v[4];
    float s = 0.f;
#pragma unroll
    for (int i = 0; i < 4; ++i) {
        v[i] = wv[(size_t)(t + i * 256) * OUTD + j];
        s += v[i] * v[i];
    }
    __shared__ float red[256];
    red[t] = s;
    __syncthreads();
    for (int off = 128; off > 0; off >>= 1) {
        if (t < off) red[t] += red[t + off];
        __syncthreads();
    }
    const float rn = 1.0f / fmaxf(sqrtf(red[0]), 1e-15f);
#pragma unroll
    for (int i = 0; i < 4; ++i)
        wnT[(size_t)j * SD + t + i * 256] = __float2bfloat16(v[i] * rn);
    if (t == 0) {
        float b2 = 2.0f * bias[j];
        cc[j] = coshf(b2);
        sb[j] = sinhf(b2);
        gg[j] = 2.0f * wg[j];
    }
}

// ---------------------------------------------------------------- token prep
// one wave per token, INTERLEAVED-CONTIGUOUS: pass p, lane i -> float4 #(64p+i)
// (lane stride 16B, fully coalesced). Pass p covers stacks {2p, 2p+1}; lanes
// 0-31 hold stack 2p, lanes 32-63 hold stack 2p+1 -> 32-lane-half butterfly.
__global__ __launch_bounds__(256) void k_tprep(
    const float* __restrict__ x, __hip_bfloat16* __restrict__ y,
    float* __restrict__ cx2, float beta_ratio, int ntok)
{
    const int wid  = threadIdx.x >> 6;
    const int lane = threadIdx.x & 63;
    const int tok  = blockIdx.x * 4 + wid;
    if (tok >= ntok) return;

    const float* xp = x + (size_t)tok * SD + 4 * lane;
    f32x4 u0 = *(const f32x4*)(xp + 0);
    f32x4 u1 = *(const f32x4*)(xp + 256);
    f32x4 u2 = *(const f32x4*)(xp + 512);
    f32x4 u3 = *(const f32x4*)(xp + 768);

    // lane-local squared sums per pass
    const float l0 = u0[0]*u0[0] + u0[1]*u0[1] + u0[2]*u0[2] + u0[3]*u0[3];
    const float l1 = u1[0]*u1[0] + u1[1]*u1[1] + u1[2]*u1[2] + u1[3]*u1[3];
    const float l2 = u2[0]*u2[0] + u2[1]*u2[1] + u2[2]*u2[2] + u2[3]*u2[3];
    const float l3 = u3[0]*u3[0] + u3[1]*u3[1] + u3[2]*u3[2] + u3[3]*u3[3];

    // per-stack sums (each 32-lane half of a pass is one stack)
    float s0 = l0, s1 = l1, s2 = l2, s3 = l3;
    RED32(s0); RED32(s1); RED32(s2); RED32(s3);

    // logmap0 scale per stack: atanh(min(xn,1-1e-7))/xn * beta
    const float n0 = fmaxf(sqrtf(s0), 1e-15f);
    const float n1 = fmaxf(sqrtf(s1), 1e-15f);
    const float n2 = fmaxf(sqrtf(s2), 1e-15f);
    const float n3 = fmaxf(sqrtf(s3), 1e-15f);
    const float t0 = fast_atanh(fminf(n0, 1.0f - 1e-7f)) * __builtin_amdgcn_rcpf(n0) * beta_ratio;
    const float t1 = fast_atanh(fminf(n1, 1.0f - 1e-7f)) * __builtin_amdgcn_rcpf(n1) * beta_ratio;
    const float t2 = fast_atanh(fminf(n2, 1.0f - 1e-7f)) * __builtin_amdgcn_rcpf(n2) * beta_ratio;
    const float t3 = fast_atanh(fminf(n3, 1.0f - 1e-7f)) * __builtin_amdgcn_rcpf(n3) * beta_ratio;

    // full-vector norm of scaled u (scale applied analytically: t_p^2 * l_p)
    float usq = t0*t0*l0 + t1*t1*l1 + t2*t2*l2 + t3*t3*l3;
    RED64(usq);
    const float un = fmaxf(sqrtf(usq), 1e-15f);
    // expmap0 scale: tanh(un)/un via exp identity
    const float e2  = __expf(2.0f * un);
    const float esc = (e2 - 1.0f) * __builtin_amdgcn_rcpf((e2 + 1.0f) * un);

    const float f0 = t0 * esc, f1 = t1 * esc, f2 = t2 * esc, f3 = t3 * esc;
    __hip_bfloat16* yp = y + (size_t)tok * SD + 4 * lane;
    *(s16x4*)(yp + 0)   = to_bf16x4(u0, f0);
    *(s16x4*)(yp + 256) = to_bf16x4(u1, f1);
    *(s16x4*)(yp + 512) = to_bf16x4(u2, f2);
    *(s16x4*)(yp + 768) = to_bf16x4(u3, f3);
    if (lane == 0) cx2[tok] = esc * esc * usq;
}

// ---------------------------------------------------------------- GEMM + MLR
// 128x128 tile, BK=64, 4 waves (2x2), per wave 4x4 mfma_16x16x32_bf16.
// LDS double-buffered; 16B-chunk XOR swizzle both-sides; named-register state.
// R12: dead isfinite guards removed (|num*rinv| <= ~2e15 -> asinh finite;
// h clamped +-20 -> sinh finite).

#define FRAG(P, r, sl) (*(const s16x8*)((P) + (r) * 128 + ((sl) << 4)))
#define MFMA(d, a, b) d = __builtin_amdgcn_mfma_f32_16x16x32_bf16(a, b, d, 0, 0, 0)

#define STAGE(base, k0) do {                                            \
    _Pragma("unroll")                                                   \
    for (int i_ = 0; i_ < 4; ++i_) {                                    \
        const int f_  = i_ * 256 + tid;                                 \
        const int r_  = f_ >> 3;                                        \
        const int ch_ = (f_ & 7) ^ (r_ & 7);                            \
        gload16(Ab + ((row0 + r_) * SD + (k0)) * 2 + ch_ * 16,          \
                AsB + (base) + f_ * 16);                                \
        gload16(Bb + ((size_t)(col0 + r_) * SD + (k0)) * 2 + ch_ * 16,  \
                BsB + (base) + f_ * 16);                                \
    }                                                                   \
} while (0)

#define EPI_ONE(Hrow, AV, R, NC) do {                                   \
    float num_ = fmaf(2.0f * (AV)[R], cb##NC, -opc_ * sbb##NC);         \
    float h_ = gb##NC * fast_asinh(num_ * rinv_);                       \
    h_ = fminf(fmaxf(h_, -20.0f), 20.0f);                               \
    const float e_ = __expf(h_);                                        \
    (Hrow)[gc##NC] = 0.5f * (e_ - __builtin_amdgcn_rcpf(e_));           \
} while (0)

#define EPI_ROW(A0, A1, A2, A3, R) do {                                 \
    const size_t gr_ = grA_ + (R);                                      \
    const float c2_  = cx2[gr_];                                        \
    const float omc_ = fmaxf(1.0f - c2_, 1e-15f);                       \
    const float opc_ = 1.0f + c2_;                                      \
    const float rinv_ = 1.0f / omc_;                                    \
    float* Hrow_ = H + gr_ * OUTD;                                      \
    EPI_ONE(Hrow_, A0, R, 0); EPI_ONE(Hrow_, A1, R, 1);                 \
    EPI_ONE(Hrow_, A2, R, 2); EPI_ONE(Hrow_, A3, R, 3);                 \
} while (0)

#define EPI_M(A0, A1, A2, A3, M) do {                                   \
    const size_t grA_ = row0 + wr * 64 + (M) * 16 + (lane >> 4) * 4;    \
    EPI_ROW(A0, A1, A2, A3, 0); EPI_ROW(A0, A1, A2, A3, 1);             \
    EPI_ROW(A0, A1, A2, A3, 2); EPI_ROW(A0, A1, A2, A3, 3);             \
} while (0)

__global__ __launch_bounds__(256, 2) void k_gemm(
    const __hip_bfloat16* __restrict__ A,   // y  [M][1024]
    const __hip_bfloat16* __restrict__ BT,  // wnT [1024][1024]
    const float* __restrict__ cx2,
    const float* __restrict__ cc, const float* __restrict__ sb,
    const float* __restrict__ gg,
    float* __restrict__ H)
{
    constexpr int BK = 64;
    constexpr int BUFB = 128 * BK * 2;      // 16 KB per buffer
    __shared__ __hip_bfloat16 As[2 * 128 * BK];
    __shared__ __hip_bfloat16 Bs[2 * 128 * BK];

    const int tid  = threadIdx.x;
    const int lane = tid & 63;
    const int wave = tid >> 6;
    const int wr = wave >> 1, wc = wave & 1;

    const int nwg = gridDim.x;
    const int L   = (blockIdx.x & 7) * (nwg >> 3) + (blockIdx.x >> 3);
    const int bx  = L & 7;
    const int by  = L >> 3;
    const size_t row0 = (size_t)by * 128;
    const int    col0 = bx * 128;

    f32x4 c00{}, c01{}, c02{}, c03{};
    f32x4 c10{}, c11{}, c12{}, c13{};
    f32x4 c20{}, c21{}, c22{}, c23{};
    f32x4 c30{}, c31{}, c32{}, c33{};

    const char* Ab = (const char*)A;
    const char* Bb = (const char*)BT;
    char* AsB = (char*)As;
    char* BsB = (char*)Bs;

    const int ra = wr * 64 + (lane & 15);
    const int rb = wc * 64 + (lane & 15);
    const int lxor = lane & 7;

    STAGE(0, 0);
    __syncthreads();

    int cur = 0;
#pragma unroll 1
    for (int t = 0; t < SD / BK; ++t) {
        const int nxt = cur ^ 1;
        if (t < SD / BK - 1) STAGE(nxt * BUFB, (t + 1) * BK);

        const char* Ap = AsB + cur * BUFB;
        const char* Bp = BsB + cur * BUFB;
#pragma unroll
        for (int ks = 0; ks < 2; ++ks) {
            const int sl = (ks * 4 + (lane >> 4)) ^ lxor;
            const s16x8 a0 = FRAG(Ap, ra,      sl);
            const s16x8 a1 = FRAG(Ap, ra + 16, sl);
            const s16x8 a2 = FRAG(Ap, ra + 32, sl);
            const s16x8 a3 = FRAG(Ap, ra + 48, sl);
            const s16x8 b0 = FRAG(Bp, rb,      sl);
            const s16x8 b1 = FRAG(Bp, rb + 16, sl);
            const s16x8 b2 = FRAG(Bp, rb + 32, sl);
            const s16x8 b3 = FRAG(Bp, rb + 48, sl);
            MFMA(c00, a0, b0); MFMA(c01, a0, b1); MFMA(c02, a0, b2); MFMA(c03, a0, b3);
            MFMA(c10, a1, b0); MFMA(c11, a1, b1); MFMA(c12, a1, b2); MFMA(c13, a1, b3);
            MFMA(c20, a2, b0); MFMA(c21, a2, b1); MFMA(c22, a2, b2); MFMA(c23, a2, b3);
            MFMA(c30, a3, b0); MFMA(c31, a3, b1); MFMA(c32, a3, b2); MFMA(c33, a3, b3);
        }
        __syncthreads();
        cur = nxt;
    }

    const int gc0 = col0 + wc * 64 +  0 + (lane & 15);
    const int gc1 = gc0 + 16;
    const int gc2 = gc0 + 32;
    const int gc3 = gc0 + 48;
    const float cb0 = cc[gc0], cb1 = cc[gc1], cb2 = cc[gc2], cb3 = cc[gc3];
    const float sbb0 = sb[gc0], sbb1 = sb[gc1], sbb2 = sb[gc2], sbb3 = sb[gc3];
    const float gb0 = gg[gc0], gb1 = gg[gc1], gb2 = gg[gc2], gb3 = gg[gc3];

    EPI_M(c00, c01, c02, c03, 0);
    EPI_M(c10, c11, c12, c13, 1);
    EPI_M(c20, c21, c22, c23, 2);
    EPI_M(c30, c31, c32, c33, 3);
}

// ---------------------------------------------------------------- projection
// one wave per token, interleaved-contiguous (lane stride 16B, coalesced)
__global__ __launch_bounds__(256) void k_proj(float* __restrict__ H, int ntok)
{
    const int wid  = threadIdx.x >> 6;
    const int lane = threadIdx.x & 63;
    const int tok  = blockIdx.x * 4 + wid;
    if (tok >= ntok) return;

    float* hp = H + (size_t)tok * OUTD + 4 * lane;
    f32x4 h0 = *(const f32x4*)(hp + 0);
    f32x4 h1 = *(const f32x4*)(hp + 256);
    f32x4 h2 = *(const f32x4*)(hp + 512);
    f32x4 h3 = *(const f32x4*)(hp + 768);

    float s = h0[0]*h0[0] + h0[1]*h0[1] + h0[2]*h0[2] + h0[3]*h0[3]
            + h1[0]*h1[0] + h1[1]*h1[1] + h1[2]*h1[2] + h1[3]*h1[3]
            + h2[0]*h2[0] + h2[1]*h2[1] + h2[2]*h2[2] + h2[3]*h2[3]
            + h3[0]*h3[0] + h3[1]*h3[1] + h3[2]*h3[2] + h3[3]*h3[3];
    RED64(s);
    const float n2 = fminf(s, 1e15f);
    const float rs = 1.0f / (1.0f + sqrtf(1.0f + n2));
    h0 *= rs; h1 *= rs; h2 *= rs; h3 *= rs;
    *(f32x4*)(hp + 0)   = h0;
    *(f32x4*)(hp + 256) = h1;
    *(f32x4*)(hp + 512) = h2;
    *(f32x4*)(hp + 768) = h3;
}

// ---------------------------------------------------------------- launch
extern "C" void kernel_launch(void* const* d_in, const int* in_sizes, int n_in,
                              void* d_out, int out_size, void* d_ws, size_t ws_size,
                              hipStream_t stream)
{
    const float* x    = (const float*)d_in[0];
    const float* wg   = (const float*)d_in[1];
    const float* wv   = (const float*)d_in[2];
    const float* bias = (const float*)d_in[3];
    float* out = (float*)d_out;

    const int ntok = in_sizes[0] / SD;   // 32768

    __hip_bfloat16* y   = (__hip_bfloat16*)d_ws;
    __hip_bfloat16* wnT = y + (size_t)ntok * SD;
    float* cx2 = (float*)(wnT + (size_t)SD * OUTD);
    float* cc  = cx2 + ntok;
    float* sb  = cc + OUTD;
    float* gg  = sb + OUTD;

    const double lg = (lgamma(512.0) - lgamma(512.5)) - (lgamma(64.0) - lgamma(64.5));
    const float beta_ratio = (float)exp(lg);

    k_wprep<<<OUTD, 256, 0, stream>>>(wv, wg, bias, wnT, cc, sb, gg);
    k_tprep<<<(ntok + 3) / 4, 256, 0, stream>>>(x, y, cx2, beta_ratio, ntok);
    k_gemm<<<(ntok / 128) * (OUTD / 128), 256, 0, stream>>>(y, wnT, cx2, cc, sb, gg, out);
    k_proj<<<(ntok + 3) / 4, 256, 0, stream>>>(out, ntok);
}